// Round 11
// baseline (84.006 us; speedup 1.0000x reference)
//
#include <hip/hip_runtime.h>
#include <stdint.h>

// x: [64, 512, 32, 32] f32. 65536 pixels, 512 channels, K=52.
// Transpose-free: each wave owns 4 pixels as float4 components; thread=lane
// loads x[(64j+lane)*1024 + px0] (j=0..7) -> the wave's 8 reg-columns hold 4
// complete pixels. Ballot selection runs per component: 3 guarded probes + 3
// bisections bracket the 52nd value; <=32 survivors -> window compact to a
// tiny per-wave LDS strip -> dual-pair 32-lane bitonic -> exact threshold ->
// tie-exact top-sum. Bounded 31-step bisection fallback => exact any input.
// No barriers, no LDS staging; 2-deep register pipeline (vA/vB), 4 blk/CU.

#define NCH   512
#define K_TOP 52
#define NBLK  1024
#define THR   256
#define WPB   4                  // waves per block
#define GW    (NBLK * WPB)       // 4096 global waves; 4 tiles each, 4 px/tile
#define P175  0x3FE00000u
#define P125  0x3FA00000u
#define P0875 0x3F600000u
#define INFB  0x7F800000u

#define UPJ(v, j, p) ((p) == 0 ? (v)[j].x : (p) == 1 ? (v)[j].y : (p) == 2 ? (v)[j].z : (v)[j].w)

static __device__ __forceinline__ int mbcnt64(uint64_t m) {
    return (int)__builtin_amdgcn_mbcnt_hi((uint32_t)(m >> 32),
            __builtin_amdgcn_mbcnt_lo((uint32_t)m, 0u));
}

__global__ __launch_bounds__(THR, 4) void hah_kernel(const float* __restrict__ x,
                                                     float* __restrict__ ws) {
    __shared__ uint32_t scr[WPB][2][64];   // per-wave 2x64-slot sort strips (2 KB)

    const int t    = threadIdx.x;
    const int lane = t & 63;
    const int w    = t >> 6;
    const int bid  = blockIdx.x;
    // bijective XCD-chunked swizzle (1024 % 8 == 0): concurrent XCD-mates are
    // pixel-adjacent -> 128B-line sharing resolves in one L2
    const int swz  = (bid & 7) * (NBLK >> 3) + (bid >> 3);
    const int g    = swz * WPB + w;

    float sgt = 0.f, relu = 0.f, topc = 0.f;
    float4 vA[8], vB[8];

    auto loadt = [&](float4 (&dst)[8], int rep) {
        const int pxg = (rep * GW + g) * 4;                 // 4 px, never crosses batch
        const float* bp = x + ((size_t)(pxg >> 10)) * (NCH * 1024) + (pxg & 1023);
        #pragma unroll
        for (int j = 0; j < 8; ++j)
            dst[j] = *reinterpret_cast<const float4*>(bp + (size_t)(64 * j + lane) * 1024);
    };

    auto process = [&](float4 (&v)[8]) {
        // relu in place + running total sum
        #pragma unroll
        for (int j = 0; j < 8; ++j) {
            v[j].x = fmaxf(v[j].x, 0.f); v[j].y = fmaxf(v[j].y, 0.f);
            v[j].z = fmaxf(v[j].z, 0.f); v[j].w = fmaxf(v[j].w, 0.f);
            relu += (v[j].x + v[j].y) + (v[j].z + v[j].w);
        }
        // ---- bracket each pixel: 3 guarded fixed probes + 3 bisections ----
        uint32_t lo[4], hi[4]; int clo[4], ctop[4];
        #pragma unroll
        for (int p = 0; p < 4; ++p) {
            uint32_t L = 0u, H = INFB; int CL = NCH, CT = 0;
            #pragma unroll
            for (int q = 0; q < 3; ++q) {
                const uint32_t mb = (q == 0) ? P175 : (q == 1) ? P125 : P0875;
                const float mf = __uint_as_float(mb);
                int c = 0;
                #pragma unroll
                for (int j = 0; j < 8; ++j) c += (int)__popcll(__ballot(UPJ(v, j, p) >= mf));
                const bool valid = (mb > L) && (mb <= H);
                const bool ge = valid && (c >= K_TOP);
                const bool lt = valid && (c < K_TOP);
                L = ge ? mb : L;          CL = ge ? c : CL;
                H = lt ? (mb - 1u) : H;   CT = lt ? c : CT;
            }
            #pragma unroll
            for (int q = 0; q < 3; ++q) {
                const uint32_t mb = (L + H + 1u) >> 1;
                const float mf = __uint_as_float(mb);
                int c = 0;
                #pragma unroll
                for (int j = 0; j < 8; ++j) c += (int)__popcll(__ballot(UPJ(v, j, p) >= mf));
                const bool ge = (c >= K_TOP);
                L = ge ? mb : L;            CL = ge ? c : CL;
                H = ge ? H : (mb - 1u);     CT = ge ? CT : c;
            }
            lo[p] = L; hi[p] = H; clo[p] = CL; ctop[p] = CT;
        }
        const bool fast = (clo[0] - ctop[0] <= 32) && (clo[1] - ctop[1] <= 32) &&
                          (clo[2] - ctop[2] <= 32) && (clo[3] - ctop[3] <= 32);
        uint32_t Tb[4];
        if (!fast) {
            // bounded exact fallback: 31 more bisections per pixel (wave-uniform)
            #pragma unroll
            for (int p = 0; p < 4; ++p) {
                uint32_t L = lo[p], H = hi[p];
                #pragma unroll 1
                for (int s = 0; s < 31; ++s) {
                    const uint32_t mb = (L + H + 1u) >> 1;
                    const float mf = __uint_as_float(mb);
                    int c = 0;
                    #pragma unroll
                    for (int j = 0; j < 8; ++j) c += (int)__popcll(__ballot(UPJ(v, j, p) >= mf));
                    const bool ge = (c >= K_TOP);
                    L = ge ? mb : L; H = ge ? H : (mb - 1u);
                }
                Tb[p] = L;
            }
        } else {
            // ---- window compact (<=32 per px) into per-wave strips ----
            scr[w][0][lane] = 0u; scr[w][1][lane] = 0u;
            #pragma unroll
            for (int p = 0; p < 4; ++p) {
                const float lof = __uint_as_float(lo[p]);
                const float hif = __uint_as_float(hi[p]);
                int base = 0;
                #pragma unroll
                for (int j = 0; j < 8; ++j) {
                    const float val = UPJ(v, j, p);
                    const bool pred = (val >= lof) && (val <= hif);
                    const uint64_t mk = __ballot(pred);
                    if (pred)
                        scr[w][p >> 1][(p & 1) * 32 + base + mbcnt64(mk)] = __float_as_uint(val);
                    base += (int)__popcll(mk);
                }
            }
            // ---- dual-pair 32-lane bitonic (px0,1 in a0; px2,3 in a1) ----
            uint32_t a0 = scr[w][0][lane], a1 = scr[w][1][lane];
            const int l = lane & 31;
            #pragma unroll
            for (int k = 2; k <= 32; k <<= 1) {
                #pragma unroll
                for (int j = k >> 1; j >= 1; j >>= 1) {
                    const bool tm = ((l & k) == 0) == ((l & j) == 0);
                    { const uint32_t o = (uint32_t)__shfl_xor((int)a0, j, 64);
                      const uint32_t mx = a0 > o ? a0 : o, mn = a0 > o ? o : a0;
                      a0 = tm ? mx : mn; }
                    { const uint32_t o = (uint32_t)__shfl_xor((int)a1, j, 64);
                      const uint32_t mx = a1 > o ? a1 : o, mn = a1 > o ? o : a1;
                      a1 = tm ? mx : mn; }
                }
            }
            Tb[0] = (uint32_t)__shfl((int)a0,      K_TOP - ctop[0] - 1, 64);
            Tb[1] = (uint32_t)__shfl((int)a0, 32 + K_TOP - ctop[1] - 1, 64);
            Tb[2] = (uint32_t)__shfl((int)a1,      K_TOP - ctop[2] - 1, 64);
            Tb[3] = (uint32_t)__shfl((int)a1, 32 + K_TOP - ctop[3] - 1, 64);
        }
        // ---- shared tie-exact pass ----
        #pragma unroll
        for (int p = 0; p < 4; ++p) {
            const float Tf = __uint_as_float(Tb[p]);
            int c = 0;
            #pragma unroll
            for (int j = 0; j < 8; ++j) {
                const float val = UPJ(v, j, p);
                c += (int)__popcll(__ballot(val > Tf));
                sgt += (val > Tf) ? val : 0.f;
            }
            topc += (float)(K_TOP - c) * Tf;
        }
    };

    // ---- 2-deep register pipeline, statically unrolled (no runtime indexing) ----
    loadt(vA, 0);
    loadt(vB, 1);
    __builtin_amdgcn_sched_barrier(0);
    process(vA);
    loadt(vA, 2);
    __builtin_amdgcn_sched_barrier(0);
    process(vB);
    loadt(vB, 3);
    __builtin_amdgcn_sched_barrier(0);
    process(vA);
    process(vB);

    // ---- wave reduce + one partial per wave ----
    #pragma unroll
    for (int m = 32; m >= 1; m >>= 1) {
        sgt  += __shfl_xor(sgt,  m, 64);
        relu += __shfl_xor(relu, m, 64);
    }
    if (lane == 0) {
        const float C1 = (1.0f / (float)K_TOP + 1.0f / (float)(NCH - K_TOP));
        const float C2 = (1.0f / (float)(NCH - K_TOP));
        ws[g] = (sgt + topc) * C1 - relu * C2;
    }
}

__global__ void hah_reduce_kernel(const float* __restrict__ ws, float* __restrict__ out) {
    __shared__ float red[256];
    float s = 0.0f;
    #pragma unroll
    for (int k = 0; k < GW / 256; ++k) s += ws[threadIdx.x + 256 * k];
    red[threadIdx.x] = s;
    __syncthreads();
    for (int step = 128; step >= 1; step >>= 1) {
        if (threadIdx.x < step) red[threadIdx.x] += red[threadIdx.x + step];
        __syncthreads();
    }
    if (threadIdx.x == 0) out[0] = red[0] * (1.0f / 65536.0f);
}

extern "C" void kernel_launch(void* const* d_in, const int* in_sizes, int n_in,
                              void* d_out, int out_size, void* d_ws, size_t ws_size,
                              hipStream_t stream) {
    const float* x = (const float*)d_in[0];
    float* out = (float*)d_out;
    float* ws  = (float*)d_ws;   // 4096 float partials (16 KB)

    hah_kernel<<<NBLK, THR, 0, stream>>>(x, ws);
    hah_reduce_kernel<<<1, 256, 0, stream>>>(ws, out);
}